// Round 1
// baseline (787.765 us; speedup 1.0000x reference)
//
#include <hip/hip_runtime.h>
#include <hip/hip_bf16.h>

// NT-Xent loss, BATCH=4096, N=8192, D=512, TEMP=0.1
// loss = mean_i [ logsumexp_{j!=i} sim[i,j] - sim[i,partner(i)] ]
// acc  = mean_i [ sim[i,partner(i)] >= max_{j!=i,partner} sim[i,j] ]
// sim = (msg_norm . img_norm^T) / TEMP ; fold 10x into msg side.

#define NROWS 8192
#define BATCHD 4096
#define DIM 512
#define BM 128
#define BN 128
#define BK 16
#define SHIFT 10.0f

// monotonic float<->uint mapping (order-preserving) for atomicMax on floats
__device__ __forceinline__ unsigned f2u_ord(float f) {
    unsigned u = __float_as_uint(f);
    return (u & 0x80000000u) ? ~u : (u | 0x80000000u);
}
__device__ __forceinline__ float u2f_ord(unsigned e) {
    return (e & 0x80000000u) ? __uint_as_float(e & 0x7fffffffu) : __uint_as_float(~e);
}

__global__ __launch_bounds__(64) void normalize_rows(const float* __restrict__ in,
                                                     float* __restrict__ out,
                                                     float scale) {
    const int row = blockIdx.x;
    const int lane = threadIdx.x;
    const float* src = in + (size_t)row * DIM + lane * 8;
    float4 v0 = *(const float4*)(src);
    float4 v1 = *(const float4*)(src + 4);
    float ss = v0.x*v0.x + v0.y*v0.y + v0.z*v0.z + v0.w*v0.w
             + v1.x*v1.x + v1.y*v1.y + v1.z*v1.z + v1.w*v1.w;
    #pragma unroll
    for (int off = 1; off < 64; off <<= 1) ss += __shfl_xor(ss, off);
    const float inv = scale / fmaxf(sqrtf(ss), 1e-8f);
    float* dst = out + (size_t)row * DIM + lane * 8;
    *(float4*)(dst)     = make_float4(v0.x*inv, v0.y*inv, v0.z*inv, v0.w*inv);
    *(float4*)(dst + 4) = make_float4(v1.x*inv, v1.y*inv, v1.z*inv, v1.w*inv);
}

__global__ void init_rows(float* __restrict__ rowsum, unsigned* __restrict__ rowmax) {
    const int i = blockIdx.x * blockDim.x + threadIdx.x;
    if (i < NROWS) {
        rowsum[i] = 0.f;
        rowmax[i] = 0u;   // encodes "most negative"
    }
}

// A = mn (already x10), B = im.  sim[i][j] = sum_k A[i][k]*B[j][k]
__global__ __launch_bounds__(256) void simloss_gemm(const float* __restrict__ A,
                                                    const float* __restrict__ B,
                                                    float* __restrict__ rowsum,
                                                    unsigned* __restrict__ rowmax,
                                                    float* __restrict__ rowpos) {
    __shared__ float As[BK][BM];
    __shared__ float Bs[BK][BN];
    const int rowBase = blockIdx.y * BM;
    const int colBase = blockIdx.x * BN;
    const int tid = threadIdx.x;
    const int tx = tid & 15;
    const int ty = tid >> 4;

    float acc[8][8];
    #pragma unroll
    for (int m = 0; m < 8; ++m)
        #pragma unroll
        for (int n = 0; n < 8; ++n) acc[m][n] = 0.f;

    for (int k0 = 0; k0 < DIM; k0 += BK) {
        #pragma unroll
        for (int q = 0; q < 2; ++q) {
            const int idx = tid * 2 + q;      // 0..511
            const int r = idx >> 2;           // 0..127
            const int kv = (idx & 3) << 2;    // 0,4,8,12
            const float4 av = *(const float4*)(A + (size_t)(rowBase + r) * DIM + k0 + kv);
            As[kv+0][r] = av.x; As[kv+1][r] = av.y; As[kv+2][r] = av.z; As[kv+3][r] = av.w;
            const float4 bv = *(const float4*)(B + (size_t)(colBase + r) * DIM + k0 + kv);
            Bs[kv+0][r] = bv.x; Bs[kv+1][r] = bv.y; Bs[kv+2][r] = bv.z; Bs[kv+3][r] = bv.w;
        }
        __syncthreads();
        #pragma unroll
        for (int kk = 0; kk < BK; ++kk) {
            float a[8], b[8];
            *(float4*)&a[0] = *(const float4*)&As[kk][ty*8];
            *(float4*)&a[4] = *(const float4*)&As[kk][ty*8+4];
            *(float4*)&b[0] = *(const float4*)&Bs[kk][tx*8];
            *(float4*)&b[4] = *(const float4*)&Bs[kk][tx*8+4];
            #pragma unroll
            for (int m = 0; m < 8; ++m)
                #pragma unroll
                for (int n = 0; n < 8; ++n)
                    acc[m][n] = fmaf(a[m], b[n], acc[m][n]);
        }
        __syncthreads();
    }

    // Epilogue: per-row {sum exp(s-10) over j!=i, max over negatives, positive}
    const int baseRow = rowBase + ty * 8;
    const int baseCol = colBase + tx * 8;
    #pragma unroll
    for (int m = 0; m < 8; ++m) {
        const int i = baseRow + m;
        const int partner = (i < BATCHD) ? (i + BATCHD) : (i - BATCHD);
        float sum = 0.f;
        float mx = -1e30f;
        float pos = 0.f;
        bool hasPos = false;
        #pragma unroll
        for (int n = 0; n < 8; ++n) {
            const int j = baseCol + n;
            const float s = acc[m][n];
            if (j == i) continue;                  // diagonal excluded entirely
            sum += __expf(s - SHIFT);
            if (j == partner) { pos = s; hasPos = true; }
            else mx = fmaxf(mx, s);
        }
        // reduce across the 16 tx-lanes sharing this row
        #pragma unroll
        for (int off = 1; off < 16; off <<= 1) {
            sum += __shfl_xor(sum, off);
            mx = fmaxf(mx, __shfl_xor(mx, off));
        }
        if (tx == 0) {
            atomicAdd(&rowsum[i], sum);
            atomicMax(&rowmax[i], f2u_ord(mx));
        }
        if (hasPos) rowpos[i] = pos;   // exactly one writer grid-wide per row
    }
}

__global__ __launch_bounds__(256) void finalize_k(const float* __restrict__ rowsum,
                                                  const unsigned* __restrict__ rowmax,
                                                  const float* __restrict__ rowpos,
                                                  float* __restrict__ out) {
    const int tid = threadIdx.x;
    float lossAcc = 0.f, hitAcc = 0.f;
    for (int i = tid; i < NROWS; i += 256) {
        const float lse = SHIFT + logf(rowsum[i]);
        const float pos = rowpos[i];
        lossAcc += lse - pos;
        hitAcc += (pos >= u2f_ord(rowmax[i])) ? 1.f : 0.f;
    }
    __shared__ float sl[256], sa[256];
    sl[tid] = lossAcc; sa[tid] = hitAcc;
    __syncthreads();
    for (int s = 128; s > 0; s >>= 1) {
        if (tid < s) { sl[tid] += sl[tid + s]; sa[tid] += sa[tid + s]; }
        __syncthreads();
    }
    if (tid == 0) {
        out[0] = sl[0] / (float)NROWS;
        out[1] = sa[0] / (float)NROWS;
    }
}

extern "C" void kernel_launch(void* const* d_in, const int* in_sizes, int n_in,
                              void* d_out, int out_size, void* d_ws, size_t ws_size,
                              hipStream_t stream) {
    const float* msg = (const float*)d_in[0];
    const float* img = (const float*)d_in[1];
    float* out = (float*)d_out;

    char* ws = (char*)d_ws;
    const size_t matBytes = (size_t)NROWS * DIM * sizeof(float);   // 16 MB
    float* mn = (float*)ws;
    float* im = (float*)(ws + matBytes);
    float* rowsum = (float*)(ws + 2 * matBytes);
    unsigned* rowmax = (unsigned*)(ws + 2 * matBytes + NROWS * sizeof(float));
    float* rowpos = (float*)(ws + 2 * matBytes + 2 * NROWS * sizeof(float));

    normalize_rows<<<NROWS, 64, 0, stream>>>(msg, mn, 10.0f);  // fold 1/TEMP into msg
    normalize_rows<<<NROWS, 64, 0, stream>>>(img, im, 1.0f);
    init_rows<<<NROWS / 256, 256, 0, stream>>>(rowsum, rowmax);

    dim3 grid(NROWS / BN, NROWS / BM);
    simloss_gemm<<<grid, 256, 0, stream>>>(mn, im, rowsum, rowmax, rowpos);

    finalize_k<<<1, 256, 0, stream>>>(rowsum, rowmax, rowpos, out);
}

// Round 2
// 257.731 us; speedup vs baseline: 3.0565x; 3.0565x over previous
//
#include <hip/hip_runtime.h>
#include <hip/hip_bf16.h>

// NT-Xent, BATCH=4096, N=8192, D=512, TEMP=0.1 — bf16 MFMA version.
// loss = mean_i [ logsumexp_{j!=i} sim[i,j] - sim[i,partner(i)] ]
// acc  = mean_i [ sim[i,partner(i)] >= max_{j!=i,partner} sim[i,j] ]
// sim = (msg_n . img_n^T)/TEMP, 10x folded into msg side before bf16 cast.

#define NROWS 8192
#define BATCHD 4096
#define DIM 512
#define BM 128
#define BN 128
#define BK 32
#define SHIFT 10.0f

typedef short bf16x8 __attribute__((ext_vector_type(8)));
typedef float f32x4 __attribute__((ext_vector_type(4)));

#define GLDS(g, l)                                                             \
    __builtin_amdgcn_global_load_lds(                                          \
        (const __attribute__((address_space(1))) void*)(g),                    \
        (__attribute__((address_space(3))) void*)(l), 16, 0, 0)

__device__ __forceinline__ unsigned f2u_ord(float f) {
    unsigned u = __float_as_uint(f);
    return (u & 0x80000000u) ? ~u : (u | 0x80000000u);
}
__device__ __forceinline__ float u2f_ord(unsigned e) {
    return (e & 0x80000000u) ? __uint_as_float(e & 0x7fffffffu) : __uint_as_float(~e);
}
__device__ __forceinline__ short f2bf(float f) {  // RNE f32 -> bf16 bits
    unsigned u = __float_as_uint(f);
    return (short)((u + 0x7fffu + ((u >> 16) & 1u)) >> 16);
}

__global__ __launch_bounds__(64) void normalize_bf16(const float* __restrict__ in,
                                                     short* __restrict__ out,
                                                     float scale) {
    const int row = blockIdx.x;
    const int lane = threadIdx.x;
    const float* src = in + (size_t)row * DIM + lane * 8;
    float4 v0 = *(const float4*)(src);
    float4 v1 = *(const float4*)(src + 4);
    float ss = v0.x*v0.x + v0.y*v0.y + v0.z*v0.z + v0.w*v0.w
             + v1.x*v1.x + v1.y*v1.y + v1.z*v1.z + v1.w*v1.w;
    #pragma unroll
    for (int off = 1; off < 64; off <<= 1) ss += __shfl_xor(ss, off);
    const float inv = scale / fmaxf(sqrtf(ss), 1e-8f);
    float vv[8] = {v0.x, v0.y, v0.z, v0.w, v1.x, v1.y, v1.z, v1.w};
    bf16x8 o;
    #pragma unroll
    for (int j = 0; j < 8; ++j) o[j] = f2bf(vv[j] * inv);
    *(bf16x8*)(out + (size_t)row * DIM + lane * 8) = o;
}

__global__ void init_rows(float* __restrict__ rowsum, unsigned* __restrict__ rowmax) {
    const int i = blockIdx.x * blockDim.x + threadIdx.x;
    if (i < NROWS) {
        rowsum[i] = 0.f;
        rowmax[i] = 0u;  // encodes "most negative"
    }
}

// A = msg_n*10 (bf16 bits), B = img_n (bf16 bits); both row-major [8192][512].
// 128x128 tile, BK=32, 4 waves (2x2 of 64x64), mfma_f32_16x16x32_bf16.
__global__ __launch_bounds__(256) void simloss_mfma(const short* __restrict__ A,
                                                    const short* __restrict__ B,
                                                    float* __restrict__ rowsum,
                                                    unsigned* __restrict__ rowmax,
                                                    float* __restrict__ rowpos) {
    __shared__ short As[BM * BK];  // 8 KB, rows of 32 bf16 in 4 16B chunk-slots
    __shared__ short Bs[BN * BK];  // chunk-slot p of row r holds logical chunk p^((r>>1)&3)

    const int tid = threadIdx.x;
    const int lane = tid & 63;
    const int wid = tid >> 6;
    const int wr = wid >> 1, wc = wid & 1;
    const int rowBase = blockIdx.y * BM;
    const int colBase = blockIdx.x * BN;

    // --- staging (pre-swizzled global source, linear LDS dest) ---
    const int srow = tid >> 2;                        // 0..63 (row within half-tile)
    const int slot = tid & 3;                         // 16B chunk slot in LDS
    const int gchunk = slot ^ ((srow >> 1) & 3);      // logical k-chunk to fetch
    const short* gA = A + (size_t)(rowBase + srow) * DIM + gchunk * 8;
    const short* gB = B + (size_t)(colBase + srow) * DIM + gchunk * 8;
    short* ldsA = &As[tid * 8];                       // lane-linear 16B each
    short* ldsB = &Bs[tid * 8];

    // --- fragment read offsets (shorts), same XOR on read side ---
    const int g = lane >> 4;          // k-block 0..3
    const int r16 = lane & 15;
    const int swz = (r16 >> 1) & 3;
    const int aoff = (wr * 64 + r16) * BK + ((g ^ swz) * 8);
    const int boff = (wc * 64 + r16) * BK + ((g ^ swz) * 8);

    f32x4 acc[4][4] = {};

    for (int k0 = 0; k0 < DIM; k0 += BK) {
        #pragma unroll
        for (int q = 0; q < 2; ++q) {
            GLDS(gA + (size_t)q * 64 * DIM + k0, ldsA + q * 2048);
            GLDS(gB + (size_t)q * 64 * DIM + k0, ldsB + q * 2048);
        }
        __syncthreads();   // vmcnt drain + barrier: tile staged

        bf16x8 af[4], bfr[4];
        #pragma unroll
        for (int m = 0; m < 4; ++m) af[m] = *(const bf16x8*)&As[aoff + m * 16 * BK];
        #pragma unroll
        for (int n = 0; n < 4; ++n) bfr[n] = *(const bf16x8*)&Bs[boff + n * 16 * BK];
        #pragma unroll
        for (int m = 0; m < 4; ++m)
            #pragma unroll
            for (int n = 0; n < 4; ++n)
                acc[m][n] = __builtin_amdgcn_mfma_f32_16x16x32_bf16(af[m], bfr[n],
                                                                    acc[m][n], 0, 0, 0);
        __syncthreads();   // all ds_reads done before next stage overwrites
    }

    // --- fused epilogue ---
    // C/D layout: col = lane&15, row = (lane>>4)*4 + reg  [m89 verified]
    const int baseRowW = rowBase + wr * 64 + g * 4;
    const int baseColW = colBase + wc * 64 + r16;
    #pragma unroll
    for (int m = 0; m < 4; ++m) {
        #pragma unroll
        for (int reg = 0; reg < 4; ++reg) {
            const int i = baseRowW + m * 16 + reg;
            const int partner = i ^ BATCHD;
            float sum = 0.f, mx = -1e30f;
            #pragma unroll
            for (int n = 0; n < 4; ++n) {
                const int j = baseColW + n * 16;
                const float s = acc[m][n][reg];
                const bool isDiag = (j == i);
                const bool isPos = (j == partner);
                float e = __expf(s - SHIFT);
                if (isDiag) e = 0.f;
                sum += e;
                if (!isDiag && !isPos) mx = fmaxf(mx, s);
                if (isPos) rowpos[i] = s;   // exactly one writer grid-wide
            }
            #pragma unroll
            for (int off = 1; off < 16; off <<= 1) {
                sum += __shfl_xor(sum, off);
                mx = fmaxf(mx, __shfl_xor(mx, off));
            }
            if (r16 == 0) {
                atomicAdd(&rowsum[i], sum);
                atomicMax(&rowmax[i], f2u_ord(mx));
            }
        }
    }
}

__global__ __launch_bounds__(256) void finalize_k(const float* __restrict__ rowsum,
                                                  const unsigned* __restrict__ rowmax,
                                                  const float* __restrict__ rowpos,
                                                  float* __restrict__ out) {
    const int tid = threadIdx.x;
    float lossAcc = 0.f, hitAcc = 0.f;
    for (int i = tid; i < NROWS; i += 256) {
        const float lse = SHIFT + logf(rowsum[i]);
        const float pos = rowpos[i];
        lossAcc += lse - pos;
        hitAcc += (pos >= u2f_ord(rowmax[i])) ? 1.f : 0.f;
    }
    __shared__ float sl[256], sa[256];
    sl[tid] = lossAcc; sa[tid] = hitAcc;
    __syncthreads();
    for (int s = 128; s > 0; s >>= 1) {
        if (tid < s) { sl[tid] += sl[tid + s]; sa[tid] += sa[tid + s]; }
        __syncthreads();
    }
    if (tid == 0) {
        out[0] = sl[0] / (float)NROWS;
        out[1] = sa[0] / (float)NROWS;
    }
}

extern "C" void kernel_launch(void* const* d_in, const int* in_sizes, int n_in,
                              void* d_out, int out_size, void* d_ws, size_t ws_size,
                              hipStream_t stream) {
    const float* msg = (const float*)d_in[0];
    const float* img = (const float*)d_in[1];
    float* out = (float*)d_out;

    char* ws = (char*)d_ws;
    const size_t matBytes = (size_t)NROWS * DIM * sizeof(short);  // 8 MB
    short* mnb = (short*)ws;
    short* imb = (short*)(ws + matBytes);
    float* rowsum = (float*)(ws + 2 * matBytes);
    unsigned* rowmax = (unsigned*)(ws + 2 * matBytes + NROWS * sizeof(float));
    float* rowpos = (float*)(ws + 2 * matBytes + 2 * NROWS * sizeof(float));

    normalize_bf16<<<NROWS, 64, 0, stream>>>(msg, mnb, 10.0f);  // fold 1/TEMP
    normalize_bf16<<<NROWS, 64, 0, stream>>>(img, imb, 1.0f);
    init_rows<<<NROWS / 256, 256, 0, stream>>>(rowsum, rowmax);

    dim3 grid(NROWS / BN, NROWS / BM);
    simloss_mfma<<<grid, 256, 0, stream>>>(mnb, imb, rowsum, rowmax, rowpos);

    finalize_k<<<1, 256, 0, stream>>>(rowsum, rowmax, rowpos, out);
}

// Round 3
// 199.528 us; speedup vs baseline: 3.9481x; 1.2917x over previous
//
#include <hip/hip_runtime.h>
#include <hip/hip_bf16.h>

// NT-Xent, BATCH=4096, N=8192, D=512, TEMP=0.1 — bf16 MFMA, 2-phase dbuf.
// loss = mean_i [ logsumexp_{j!=i} sim[i,j] - sim[i,partner(i)] ]
// acc  = mean_i [ sim[i,partner(i)] >= max_{j!=i,partner} sim[i,j] ]
// sim = (msg_n . img_n^T)/TEMP, 10x folded into msg side before bf16 cast.

#define NROWS 8192
#define BATCHD 4096
#define DIM 512
#define BM 128
#define BN 128
#define BK 32
#define SHIFT 10.0f

typedef short bf16x8 __attribute__((ext_vector_type(8)));
typedef float f32x4 __attribute__((ext_vector_type(4)));

#define GLDS(g, l)                                                             \
    __builtin_amdgcn_global_load_lds(                                          \
        (const __attribute__((address_space(1))) void*)(g),                    \
        (__attribute__((address_space(3))) void*)(l), 16, 0, 0)

__device__ __forceinline__ unsigned f2u_ord(float f) {
    unsigned u = __float_as_uint(f);
    return (u & 0x80000000u) ? ~u : (u | 0x80000000u);
}
__device__ __forceinline__ float u2f_ord(unsigned e) {
    return (e & 0x80000000u) ? __uint_as_float(e & 0x7fffffffu) : __uint_as_float(~e);
}
__device__ __forceinline__ short f2bf(float f) {  // RNE f32 -> bf16 bits
    unsigned u = __float_as_uint(f);
    return (short)((u + 0x7fffu + ((u >> 16) & 1u)) >> 16);
}

// one launch: blocks 0..NROWS-1 do msg (x10), NROWS..2*NROWS-1 do img (x1)
__global__ __launch_bounds__(64) void normalize_bf16_both(const float* __restrict__ msg,
                                                          const float* __restrict__ img,
                                                          short* __restrict__ mnb,
                                                          short* __restrict__ imb) {
    int row = blockIdx.x;
    const float* in;
    short* out;
    float scale;
    if (row < NROWS) { in = msg; out = mnb; scale = 10.0f; }
    else { row -= NROWS; in = img; out = imb; scale = 1.0f; }
    const int lane = threadIdx.x;
    const float* src = in + (size_t)row * DIM + lane * 8;
    float4 v0 = *(const float4*)(src);
    float4 v1 = *(const float4*)(src + 4);
    float ss = v0.x*v0.x + v0.y*v0.y + v0.z*v0.z + v0.w*v0.w
             + v1.x*v1.x + v1.y*v1.y + v1.z*v1.z + v1.w*v1.w;
    #pragma unroll
    for (int off = 1; off < 64; off <<= 1) ss += __shfl_xor(ss, off);
    const float inv = scale / fmaxf(sqrtf(ss), 1e-8f);
    float vv[8] = {v0.x, v0.y, v0.z, v0.w, v1.x, v1.y, v1.z, v1.w};
    bf16x8 o;
    #pragma unroll
    for (int j = 0; j < 8; ++j) o[j] = f2bf(vv[j] * inv);
    *(bf16x8*)(out + (size_t)row * DIM + lane * 8) = o;
}

__global__ void init_rows(float* __restrict__ rowsum, unsigned* __restrict__ rowmax,
                          float* __restrict__ accum) {
    const int i = blockIdx.x * blockDim.x + threadIdx.x;
    if (i < NROWS) {
        rowsum[i] = 0.f;
        rowmax[i] = 0u;  // encodes "most negative"
    }
    if (i < 2) accum[i] = 0.f;
}

// A = msg_n*10 (bf16 bits), B = img_n (bf16 bits); both row-major [8192][512].
// 128x128 tile, BK=32, 4 waves (2x2 of 64x64), mfma_f32_16x16x32_bf16.
// 2-phase: double-buffered LDS, STAGE(t+1) issued before COMPUTE(t),
// single vmcnt(0)+barrier (__syncthreads) per K-step.
__global__ __launch_bounds__(256) void simloss_mfma(const short* __restrict__ A,
                                                    const short* __restrict__ B,
                                                    float* __restrict__ rowsum,
                                                    unsigned* __restrict__ rowmax,
                                                    float* __restrict__ rowpos) {
    __shared__ short As[2][BM * BK];  // 2 x 8 KB
    __shared__ short Bs[2][BN * BK];  // chunk-slot p of row r holds chunk p^((r>>1)&3)

    const int tid = threadIdx.x;
    const int lane = tid & 63;
    const int wid = tid >> 6;
    const int wr = wid >> 1, wc = wid & 1;
    const int rowBase = blockIdx.y * BM;
    const int colBase = blockIdx.x * BN;

    // --- staging (pre-swizzled global source, linear LDS dest) ---
    const int srow = tid >> 2;                    // 0..63 (row within half-tile)
    const int slot = tid & 3;                     // 16B chunk slot in LDS
    const int gchunk = slot ^ ((srow >> 1) & 3);  // logical k-chunk to fetch
    const short* gA = A + (size_t)(rowBase + srow) * DIM + gchunk * 8;
    const short* gB = B + (size_t)(colBase + srow) * DIM + gchunk * 8;

    // --- fragment read offsets (shorts), same XOR on read side ---
    const int g = lane >> 4;  // k-block 0..3
    const int r16 = lane & 15;
    const int swz = (r16 >> 1) & 3;
    const int aoff = (wr * 64 + r16) * BK + ((g ^ swz) * 8);
    const int boff = (wc * 64 + r16) * BK + ((g ^ swz) * 8);

#define STAGE(c, k0)                                                \
    do {                                                            \
        GLDS(gA + (k0), &As[c][tid * 8]);                           \
        GLDS(gA + 64 * DIM + (k0), &As[c][2048 + tid * 8]);         \
        GLDS(gB + (k0), &Bs[c][tid * 8]);                           \
        GLDS(gB + 64 * DIM + (k0), &Bs[c][2048 + tid * 8]);         \
    } while (0)

    f32x4 acc[4][4] = {};

#define COMPUTE(c)                                                           \
    do {                                                                     \
        bf16x8 af[4], bfr[4];                                                \
        _Pragma("unroll") for (int m = 0; m < 4; ++m)                        \
            af[m] = *(const bf16x8*)&As[c][aoff + m * 16 * BK];              \
        _Pragma("unroll") for (int n = 0; n < 4; ++n)                        \
            bfr[n] = *(const bf16x8*)&Bs[c][boff + n * 16 * BK];             \
        __builtin_amdgcn_s_setprio(1);                                       \
        _Pragma("unroll") for (int m = 0; m < 4; ++m)                        \
            _Pragma("unroll") for (int n = 0; n < 4; ++n)                    \
                acc[m][n] = __builtin_amdgcn_mfma_f32_16x16x32_bf16(         \
                    af[m], bfr[n], acc[m][n], 0, 0, 0);                      \
        __builtin_amdgcn_s_setprio(0);                                       \
    } while (0)

    // prologue: stage tile 0
    STAGE(0, 0);
    __syncthreads();

    #pragma unroll 2
    for (int t = 0; t < (DIM / BK) - 1; ++t) {
        const int cur = t & 1;
        STAGE(cur ^ 1, (t + 1) * BK);  // next-tile loads in flight over compute
        COMPUTE(cur);
        __syncthreads();               // vmcnt(0)+lgkmcnt(0) drain + barrier
    }
    COMPUTE((DIM / BK - 1) & 1);       // last tile, no prefetch

    // --- fused epilogue ---
    // C/D layout: col = lane&15, row = (lane>>4)*4 + reg  [m89 verified]
    const int baseRowW = rowBase + wr * 64 + g * 4;
    const int baseColW = colBase + wc * 64 + r16;
    #pragma unroll
    for (int m = 0; m < 4; ++m) {
        #pragma unroll
        for (int reg = 0; reg < 4; ++reg) {
            const int i = baseRowW + m * 16 + reg;
            const int partner = i ^ BATCHD;
            float sum = 0.f, mx = -1e30f;
            #pragma unroll
            for (int n = 0; n < 4; ++n) {
                const int j = baseColW + n * 16;
                const float s = acc[m][n][reg];
                const bool isDiag = (j == i);
                const bool isPos = (j == partner);
                float e = __expf(s - SHIFT);
                if (isDiag) e = 0.f;
                sum += e;
                if (!isDiag && !isPos) mx = fmaxf(mx, s);
                if (isPos) rowpos[i] = s;  // exactly one writer grid-wide
            }
            #pragma unroll
            for (int off = 1; off < 16; off <<= 1) {
                sum += __shfl_xor(sum, off);
                mx = fmaxf(mx, __shfl_xor(mx, off));
            }
            if (r16 == 0) {
                atomicAdd(&rowsum[i], sum);
                atomicMax(&rowmax[i], f2u_ord(mx));
            }
        }
    }
#undef STAGE
#undef COMPUTE
}

// 32 blocks x 256 threads: one row per thread, block-reduce, atomic combine.
__global__ __launch_bounds__(256) void finalize_partial(const float* __restrict__ rowsum,
                                                        const unsigned* __restrict__ rowmax,
                                                        const float* __restrict__ rowpos,
                                                        float* __restrict__ accum) {
    const int tid = threadIdx.x;
    const int i = blockIdx.x * 256 + tid;
    const float lse = SHIFT + logf(rowsum[i]);
    const float pos = rowpos[i];
    float lossAcc = lse - pos;
    float hitAcc = (pos >= u2f_ord(rowmax[i])) ? 1.f : 0.f;
    __shared__ float sl[256], sa[256];
    sl[tid] = lossAcc; sa[tid] = hitAcc;
    __syncthreads();
    for (int s = 128; s > 0; s >>= 1) {
        if (tid < s) { sl[tid] += sl[tid + s]; sa[tid] += sa[tid + s]; }
        __syncthreads();
    }
    if (tid == 0) {
        atomicAdd(&accum[0], sl[0]);
        atomicAdd(&accum[1], sa[0]);
    }
}

__global__ void finalize_write(const float* __restrict__ accum, float* __restrict__ out) {
    if (threadIdx.x == 0) {
        out[0] = accum[0] / (float)NROWS;
        out[1] = accum[1] / (float)NROWS;
    }
}

extern "C" void kernel_launch(void* const* d_in, const int* in_sizes, int n_in,
                              void* d_out, int out_size, void* d_ws, size_t ws_size,
                              hipStream_t stream) {
    const float* msg = (const float*)d_in[0];
    const float* img = (const float*)d_in[1];
    float* out = (float*)d_out;

    char* ws = (char*)d_ws;
    const size_t matBytes = (size_t)NROWS * DIM * sizeof(short);  // 8 MB
    short* mnb = (short*)ws;
    short* imb = (short*)(ws + matBytes);
    float* rowsum = (float*)(ws + 2 * matBytes);
    unsigned* rowmax = (unsigned*)(ws + 2 * matBytes + NROWS * sizeof(float));
    float* rowpos = (float*)(ws + 2 * matBytes + 2 * NROWS * sizeof(float));
    float* accum = (float*)(ws + 2 * matBytes + 3 * NROWS * sizeof(float));

    normalize_bf16_both<<<2 * NROWS, 64, 0, stream>>>(msg, img, mnb, imb);
    init_rows<<<NROWS / 256, 256, 0, stream>>>(rowsum, rowmax, accum);

    dim3 grid(NROWS / BN, NROWS / BM);
    simloss_mfma<<<grid, 256, 0, stream>>>(mnb, imb, rowsum, rowmax, rowpos);

    finalize_partial<<<NROWS / 256, 256, 0, stream>>>(rowsum, rowmax, rowpos, accum);
    finalize_write<<<1, 64, 0, stream>>>(accum, out);
}

// Round 4
// 125.736 us; speedup vs baseline: 6.2652x; 1.5869x over previous
//
#include <hip/hip_runtime.h>
#include <hip/hip_bf16.h>

// NT-Xent, BATCH=4096, N=8192, D=512, TEMP=0.1 — bf16 MFMA, 256^2 tile,
// 4-phase/K-tile schedule with counted vmcnt (T3+T4) + setprio (T5).
// loss = mean_i [ logsumexp_{j!=i} sim[i,j] - sim[i,partner(i)] ]
// acc  = mean_i [ sim[i,partner(i)] >= max_{j!=i,partner} sim[i,j] ]
// sim = (msg_n . img_n^T)/TEMP, 10x folded into msg side before bf16 cast.

#define NROWS 8192
#define BATCHD 4096
#define DIM 512
#define BM 256
#define BN 256
#define BK 64
#define NT (DIM / BK)   // 8 K-tiles
#define SHIFT 10.0f

typedef short bf16x8 __attribute__((ext_vector_type(8)));
typedef float f32x4 __attribute__((ext_vector_type(4)));

#define GLDS(g, l)                                                             \
    __builtin_amdgcn_global_load_lds(                                          \
        (const __attribute__((address_space(1))) void*)(g),                    \
        (__attribute__((address_space(3))) void*)(l), 16, 0, 0)

__device__ __forceinline__ unsigned f2u_ord(float f) {
    unsigned u = __float_as_uint(f);
    return (u & 0x80000000u) ? ~u : (u | 0x80000000u);
}
__device__ __forceinline__ float u2f_ord(unsigned e) {
    return (e & 0x80000000u) ? __uint_as_float(e & 0x7fffffffu) : __uint_as_float(~e);
}
__device__ __forceinline__ short f2bf(float f) {  // RNE f32 -> bf16 bits
    unsigned u = __float_as_uint(f);
    return (short)((u + 0x7fffu + ((u >> 16) & 1u)) >> 16);
}

// one launch: blocks 0..NROWS-1 do msg (x10), NROWS..2*NROWS-1 do img (x1)
__global__ __launch_bounds__(64) void normalize_bf16_both(const float* __restrict__ msg,
                                                          const float* __restrict__ img,
                                                          short* __restrict__ mnb,
                                                          short* __restrict__ imb) {
    int row = blockIdx.x;
    const float* in;
    short* out;
    float scale;
    if (row < NROWS) { in = msg; out = mnb; scale = 10.0f; }
    else { row -= NROWS; in = img; out = imb; scale = 1.0f; }
    const int lane = threadIdx.x;
    const float* src = in + (size_t)row * DIM + lane * 8;
    float4 v0 = *(const float4*)(src);
    float4 v1 = *(const float4*)(src + 4);
    float ss = v0.x*v0.x + v0.y*v0.y + v0.z*v0.z + v0.w*v0.w
             + v1.x*v1.x + v1.y*v1.y + v1.z*v1.z + v1.w*v1.w;
    #pragma unroll
    for (int off = 1; off < 64; off <<= 1) ss += __shfl_xor(ss, off);
    const float inv = scale / fmaxf(sqrtf(ss), 1e-8f);
    float vv[8] = {v0.x, v0.y, v0.z, v0.w, v1.x, v1.y, v1.z, v1.w};
    bf16x8 o;
    #pragma unroll
    for (int j = 0; j < 8; ++j) o[j] = f2bf(vv[j] * inv);
    *(bf16x8*)(out + (size_t)row * DIM + lane * 8) = o;
}

__global__ void init_rows(float* __restrict__ rowsum, unsigned* __restrict__ rowmax,
                          float* __restrict__ accum) {
    const int i = blockIdx.x * blockDim.x + threadIdx.x;
    if (i < NROWS) {
        rowsum[i] = 0.f;
        rowmax[i] = 0u;  // encodes "most negative"
    }
    if (i < 2) accum[i] = 0.f;
}

// A = msg_n*10 (bf16), B = img_n (bf16); row-major [8192][512].
// 256x256 tile, 8 waves (2M x 4N), BK=64 as 2 K-halves of 32.
// Per K-half LDS layout: [256 rows][4 chunks of 16B], chunk ^= (row>>1)&3
// (round-2-verified 0-conflict layout); linear GLDS dest, pre-swizzled source.
__global__ __launch_bounds__(512, 2) void simloss_mfma(const short* __restrict__ A,
                                                       const short* __restrict__ B,
                                                       float* __restrict__ rowsum,
                                                       unsigned* __restrict__ rowmax,
                                                       float* __restrict__ rowpos) {
    __shared__ short As[2][2][BM * 32];  // [buf][khalf][256*32] = 64 KB
    __shared__ short Bs[2][2][BN * 32];  // 64 KB

    const int tid = threadIdx.x;
    const int lane = tid & 63;
    const int g = lane >> 4;     // k-chunk 0..3 within a K-half
    const int r16 = lane & 15;
    const int wid = tid >> 6;
    const int wr = wid >> 2;     // 0..1  (M waves)
    const int wc = wid & 3;      // 0..3  (N waves)

    // XCD-aware remap: 1024 blocks, contiguous chunk of 128 per XCD
    const int bid = blockIdx.x;
    const int nb = (bid & 7) * 128 + (bid >> 3);
    const int bx = nb & 31, by = nb >> 5;
    const int rowBase = by * BM;
    const int colBase = bx * BN;

    // staging: slot s = q*512+tid; row=s>>2; stored chunk=s&3;
    // logical chunk fetched = stored ^ ((row>>1)&3)  [inverse of read swizzle]
    const int s0 = tid, s1 = 512 + tid;
    const int row0 = s0 >> 2, row1 = s1 >> 2;
    const int c0 = (s0 & 3) ^ ((row0 >> 1) & 3);
    const int c1 = (s1 & 3) ^ ((row1 >> 1) & 3);
    const short* gA0 = A + (size_t)(rowBase + row0) * DIM + c0 * 8;
    const short* gA1 = A + (size_t)(rowBase + row1) * DIM + c1 * 8;
    const short* gB0 = B + (size_t)(colBase + row0) * DIM + c0 * 8;
    const short* gB1 = B + (size_t)(colBase + row1) * DIM + c1 * 8;

#define STAGE_A(b, kh, koff)                                   \
    do {                                                       \
        GLDS(gA0 + (koff) + (kh) * 32, &As[b][kh][tid * 8]);   \
        GLDS(gA1 + (koff) + (kh) * 32, &As[b][kh][4096 + tid * 8]); \
    } while (0)
#define STAGE_B(b, kh, koff)                                   \
    do {                                                       \
        GLDS(gB0 + (koff) + (kh) * 32, &Bs[b][kh][tid * 8]);   \
        GLDS(gB1 + (koff) + (kh) * 32, &Bs[b][kh][4096 + tid * 8]); \
    } while (0)

    // fragment read bases (elements); same XOR on read side
    const int swz = (r16 >> 1) & 3;
    const int aBase = (wr * 128 + r16) * 32 + ((g ^ swz) * 8);
    const int bBase = (wc * 64 + r16) * 32 + ((g ^ swz) * 8);

    f32x4 acc[8][4] = {};
    bf16x8 af[4], bfr[4];

#define DS_A(b, ks, mh)                                                        \
    do {                                                                       \
        _Pragma("unroll") for (int m = 0; m < 4; ++m)                          \
            af[m] = *(const bf16x8*)&As[b][ks][aBase + (mh) * 2048 + m * 512]; \
    } while (0)
#define DS_B(b, ks)                                                            \
    do {                                                                       \
        _Pragma("unroll") for (int n = 0; n < 4; ++n)                          \
            bfr[n] = *(const bf16x8*)&Bs[b][ks][bBase + n * 512];              \
    } while (0)
#define MFMA16(mh)                                                             \
    do {                                                                       \
        __builtin_amdgcn_s_setprio(1);                                         \
        _Pragma("unroll") for (int m = 0; m < 4; ++m)                          \
            _Pragma("unroll") for (int n = 0; n < 4; ++n)                      \
                acc[(mh) * 4 + m][n] = __builtin_amdgcn_mfma_f32_16x16x32_bf16(\
                    af[m], bfr[n], acc[(mh) * 4 + m][n], 0, 0, 0);             \
        __builtin_amdgcn_s_setprio(0);                                         \
    } while (0)
#define VMCNT(n) asm volatile("s_waitcnt vmcnt(" #n ")" ::: "memory")
#define BAR() __builtin_amdgcn_s_barrier()

    // prologue: stage tile 0 (A-kh0, B-kh0, A-kh1, B-kh1) into buf 0
    STAGE_A(0, 0, 0);
    STAGE_B(0, 0, 0);
    STAGE_A(0, 1, 0);
    STAGE_B(0, 1, 0);
    VMCNT(4);  // oldest 4 instr = A-kh0,B-kh0 landed
    BAR();

    for (int t = 0; t < NT; ++t) {
        const int b = t & 1;
        const int koff = (t + 1) * BK;
        const bool st = (t + 1 < NT);
        // P0: ks=0, m-half 0
        DS_A(b, 0, 0);
        DS_B(b, 0);
        if (st) STAGE_A(b ^ 1, 0, koff);
        BAR();
        MFMA16(0);
        BAR();
        // P1: ks=0, m-half 1
        DS_A(b, 0, 1);
        if (st) STAGE_B(b ^ 1, 0, koff);
        BAR();
        MFMA16(1);
        if (st) VMCNT(4);   // drain this tile's kh1 pair (issued last tile)
        else    VMCNT(0);   // tail: nothing newer in flight
        BAR();
        // P2: ks=1, m-half 0
        DS_A(b, 1, 0);
        DS_B(b, 1);
        if (st) STAGE_A(b ^ 1, 1, koff);
        BAR();
        MFMA16(0 + 0);      // mh=0 quadrant again, ks=1 data
        BAR();
        // P3: ks=1, m-half 1
        DS_A(b, 1, 1);
        if (st) STAGE_B(b ^ 1, 1, koff);
        BAR();
        MFMA16(1);
        if (st) VMCNT(4);   // next tile's kh0 pair landed before its P0 reads
        BAR();
    }

    // ---- fused epilogue ----
    // C/D layout: col = lane&15 (r16), row = g*4 + reg  [m89 verified]
    float* ssum = (float*)&As[0][0][0];   // 256*4 floats
    float* smx = ssum + 1024;             // 256*4 floats
    const int baseRowW = rowBase + wr * 128 + g * 4;
    const int baseColW = colBase + wc * 64 + r16;
    #pragma unroll
    for (int m = 0; m < 8; ++m) {
        #pragma unroll
        for (int reg = 0; reg < 4; ++reg) {
            const int i = baseRowW + m * 16 + reg;
            const int partner = i ^ BATCHD;
            float sum = 0.f, mx = -1e30f;
            #pragma unroll
            for (int n = 0; n < 4; ++n) {
                const int j = baseColW + n * 16;
                const float s = acc[m][n][reg];
                const bool isDiag = (j == i);
                const bool isPos = (j == partner);
                float e = __expf(s - SHIFT);
                if (isDiag) e = 0.f;
                sum += e;
                if (!isDiag && !isPos) mx = fmaxf(mx, s);
                if (isPos) rowpos[i] = s;  // exactly one writer grid-wide
            }
            #pragma unroll
            for (int off = 1; off < 16; off <<= 1) {
                sum += __shfl_xor(sum, off);
                mx = fmaxf(mx, __shfl_xor(mx, off));
            }
            if (r16 == 0) {
                const int rloc = wr * 128 + m * 16 + g * 4 + reg;
                ssum[rloc * 4 + wc] = sum;
                smx[rloc * 4 + wc] = mx;
            }
        }
    }
    __syncthreads();
    // combine the 4 column-waves' partials: one atomic pair per row per block
    if (tid < 256) {
        const float s = ssum[tid * 4 + 0] + ssum[tid * 4 + 1] +
                        ssum[tid * 4 + 2] + ssum[tid * 4 + 3];
        const float mx = fmaxf(fmaxf(smx[tid * 4 + 0], smx[tid * 4 + 1]),
                               fmaxf(smx[tid * 4 + 2], smx[tid * 4 + 3]));
        const int i = rowBase + tid;
        atomicAdd(&rowsum[i], s);
        atomicMax(&rowmax[i], f2u_ord(mx));
    }
#undef STAGE_A
#undef STAGE_B
#undef DS_A
#undef DS_B
#undef MFMA16
#undef VMCNT
#undef BAR
}

// 32 blocks x 256 threads: one row per thread, block-reduce, atomic combine.
__global__ __launch_bounds__(256) void finalize_partial(const float* __restrict__ rowsum,
                                                        const unsigned* __restrict__ rowmax,
                                                        const float* __restrict__ rowpos,
                                                        float* __restrict__ accum) {
    const int tid = threadIdx.x;
    const int i = blockIdx.x * 256 + tid;
    const float lse = SHIFT + logf(rowsum[i]);
    const float pos = rowpos[i];
    float lossAcc = lse - pos;
    float hitAcc = (pos >= u2f_ord(rowmax[i])) ? 1.f : 0.f;
    __shared__ float sl[256], sa[256];
    sl[tid] = lossAcc; sa[tid] = hitAcc;
    __syncthreads();
    for (int s = 128; s > 0; s >>= 1) {
        if (tid < s) { sl[tid] += sl[tid + s]; sa[tid] += sa[tid + s]; }
        __syncthreads();
    }
    if (tid == 0) {
        atomicAdd(&accum[0], sl[0]);
        atomicAdd(&accum[1], sa[0]);
    }
}

__global__ void finalize_write(const float* __restrict__ accum, float* __restrict__ out) {
    if (threadIdx.x == 0) {
        out[0] = accum[0] / (float)NROWS;
        out[1] = accum[1] / (float)NROWS;
    }
}

extern "C" void kernel_launch(void* const* d_in, const int* in_sizes, int n_in,
                              void* d_out, int out_size, void* d_ws, size_t ws_size,
                              hipStream_t stream) {
    const float* msg = (const float*)d_in[0];
    const float* img = (const float*)d_in[1];
    float* out = (float*)d_out;

    char* ws = (char*)d_ws;
    const size_t matBytes = (size_t)NROWS * DIM * sizeof(short);  // 8 MB
    short* mnb = (short*)ws;
    short* imb = (short*)(ws + matBytes);
    float* rowsum = (float*)(ws + 2 * matBytes);
    unsigned* rowmax = (unsigned*)(ws + 2 * matBytes + NROWS * sizeof(float));
    float* rowpos = (float*)(ws + 2 * matBytes + 2 * NROWS * sizeof(float));
    float* accum = (float*)(ws + 2 * matBytes + 3 * NROWS * sizeof(float));

    normalize_bf16_both<<<2 * NROWS, 64, 0, stream>>>(msg, img, mnb, imb);
    init_rows<<<NROWS / 256, 256, 0, stream>>>(rowsum, rowmax, accum);

    simloss_mfma<<<(NROWS / BM) * (NROWS / BN), 512, 0, stream>>>(mnb, imb, rowsum,
                                                                  rowmax, rowpos);

    finalize_partial<<<NROWS / 256, 256, 0, stream>>>(rowsum, rowmax, rowpos, accum);
    finalize_write<<<1, 64, 0, stream>>>(accum, out);
}

// Round 5
// 117.392 us; speedup vs baseline: 6.7106x; 1.0711x over previous
//
#include <hip/hip_runtime.h>
#include <hip/hip_bf16.h>

// NT-Xent, BATCH=4096, N=8192, D=512, TEMP=0.1 — bf16 MFMA, 256^2 tile,
// 4-phase/K-tile counted-vmcnt schedule, deep prefetch + bx-major XCD stripes.
// loss = mean_i [ logsumexp_{j!=i} sim[i,j] - sim[i,partner(i)] ]
// acc  = mean_i [ sim[i,partner(i)] >= max_{j!=i,partner} sim[i,j] ]
// sim = (msg_n . img_n^T)/TEMP, 10x folded into msg side before bf16 cast.

#define NROWS 8192
#define BATCHD 4096
#define DIM 512
#define BM 256
#define BN 256
#define BK 64
#define NT (DIM / BK)   // 8 K-tiles
#define SHIFT 10.0f

typedef short bf16x8 __attribute__((ext_vector_type(8)));
typedef float f32x4 __attribute__((ext_vector_type(4)));

#define GLDS(g, l)                                                             \
    __builtin_amdgcn_global_load_lds(                                          \
        (const __attribute__((address_space(1))) void*)(g),                    \
        (__attribute__((address_space(3))) void*)(l), 16, 0, 0)

__device__ __forceinline__ unsigned f2u_ord(float f) {
    unsigned u = __float_as_uint(f);
    return (u & 0x80000000u) ? ~u : (u | 0x80000000u);
}
__device__ __forceinline__ float u2f_ord(unsigned e) {
    return (e & 0x80000000u) ? __uint_as_float(e & 0x7fffffffu) : __uint_as_float(~e);
}
__device__ __forceinline__ short f2bf(float f) {  // RNE f32 -> bf16 bits
    unsigned u = __float_as_uint(f);
    return (short)((u + 0x7fffu + ((u >> 16) & 1u)) >> 16);
}

// blocks 0..NROWS-1: msg (x10); NROWS..2*NROWS-1: img (x1).
// First 128 blocks also zero rowsum/rowmax/accum (no dependency on main work).
__global__ __launch_bounds__(64) void normalize_bf16_both(const float* __restrict__ msg,
                                                          const float* __restrict__ img,
                                                          short* __restrict__ mnb,
                                                          short* __restrict__ imb,
                                                          float* __restrict__ rowsum,
                                                          unsigned* __restrict__ rowmax,
                                                          float* __restrict__ accum) {
    if (blockIdx.x < 128) {
        const int i = blockIdx.x * 64 + threadIdx.x;
        rowsum[i] = 0.f;
        rowmax[i] = 0u;  // encodes "most negative"
        if (i < 2) accum[i] = 0.f;
    }
    int row = blockIdx.x;
    const float* in;
    short* out;
    float scale;
    if (row < NROWS) { in = msg; out = mnb; scale = 10.0f; }
    else { row -= NROWS; in = img; out = imb; scale = 1.0f; }
    const int lane = threadIdx.x;
    const float* src = in + (size_t)row * DIM + lane * 8;
    float4 v0 = *(const float4*)(src);
    float4 v1 = *(const float4*)(src + 4);
    float ss = v0.x*v0.x + v0.y*v0.y + v0.z*v0.z + v0.w*v0.w
             + v1.x*v1.x + v1.y*v1.y + v1.z*v1.z + v1.w*v1.w;
    #pragma unroll
    for (int off = 1; off < 64; off <<= 1) ss += __shfl_xor(ss, off);
    const float inv = scale / fmaxf(sqrtf(ss), 1e-8f);
    float vv[8] = {v0.x, v0.y, v0.z, v0.w, v1.x, v1.y, v1.z, v1.w};
    bf16x8 o;
    #pragma unroll
    for (int j = 0; j < 8; ++j) o[j] = f2bf(vv[j] * inv);
    *(bf16x8*)(out + (size_t)row * DIM + lane * 8) = o;
}

// A = msg_n*10 (bf16), B = img_n (bf16); row-major [8192][512].
// 256x256 tile, 8 waves (2M x 4N), BK=64 as 2 K-halves of 32.
// Per K-half LDS layout: [256 rows][4 chunks of 16B], chunk ^= (row>>1)&3
// (verified 0-conflict); linear GLDS dest, pre-swizzled global source.
__global__ __launch_bounds__(512, 2) void simloss_mfma(const short* __restrict__ A,
                                                       const short* __restrict__ B,
                                                       float* __restrict__ rowsum,
                                                       unsigned* __restrict__ rowmax,
                                                       float* __restrict__ rowpos) {
    __shared__ short As[2][2][BM * 32];  // [buf][khalf] = 64 KB
    __shared__ short Bs[2][2][BN * 32];  // 64 KB

    const int tid = threadIdx.x;
    const int lane = tid & 63;
    const int g = lane >> 4;     // k-chunk 0..3 within a K-half
    const int r16 = lane & 15;
    const int wid = tid >> 6;
    const int wr = wid >> 2;     // 0..1  (M waves)
    const int wc = wid & 3;      // 0..3  (N waves)

    // XCD stripes, bx-major traversal within each stripe:
    // XCD k owns by in [k*4, k*4+4); consecutive blocks on one XCD walk by
    // fastest, bx slowest -> L2 working set = A-stripe (1MB) + few B panels.
    const int bid = blockIdx.x;
    const int k = bid & 7;           // XCD (round-robin dispatch assumption)
    const int l = bid >> 3;          // 0..127 within stripe
    const int by = k * 4 + (l & 3);
    const int bx = l >> 2;
    const int rowBase = by * BM;
    const int colBase = bx * BN;

    // staging: slot s = q*512+tid; row=s>>2; stored chunk=s&3;
    // logical chunk fetched = stored ^ ((row>>1)&3)  [inverse of read swizzle]
    const int s0 = tid, s1 = 512 + tid;
    const int row0 = s0 >> 2, row1 = s1 >> 2;
    const int c0 = (s0 & 3) ^ ((row0 >> 1) & 3);
    const int c1 = (s1 & 3) ^ ((row1 >> 1) & 3);
    const short* gA0 = A + (size_t)(rowBase + row0) * DIM + c0 * 8;
    const short* gA1 = A + (size_t)(rowBase + row1) * DIM + c1 * 8;
    const short* gB0 = B + (size_t)(colBase + row0) * DIM + c0 * 8;
    const short* gB1 = B + (size_t)(colBase + row1) * DIM + c1 * 8;

#define STAGE_A(b, kh, koff)                                        \
    do {                                                            \
        GLDS(gA0 + (koff) + (kh) * 32, &As[b][kh][tid * 8]);        \
        GLDS(gA1 + (koff) + (kh) * 32, &As[b][kh][4096 + tid * 8]); \
    } while (0)
#define STAGE_B(b, kh, koff)                                        \
    do {                                                            \
        GLDS(gB0 + (koff) + (kh) * 32, &Bs[b][kh][tid * 8]);        \
        GLDS(gB1 + (koff) + (kh) * 32, &Bs[b][kh][4096 + tid * 8]); \
    } while (0)

    // fragment read bases (elements); same XOR on read side
    const int swz = (r16 >> 1) & 3;
    const int aBase = (wr * 128 + r16) * 32 + ((g ^ swz) * 8);
    const int bBase = (wc * 64 + r16) * 32 + ((g ^ swz) * 8);

    f32x4 acc[8][4] = {};
    bf16x8 af[4], bfr[4];

#define DS_A(b, ks, mh)                                                        \
    do {                                                                       \
        _Pragma("unroll") for (int m = 0; m < 4; ++m)                          \
            af[m] = *(const bf16x8*)&As[b][ks][aBase + (mh) * 2048 + m * 512]; \
    } while (0)
#define DS_B(b, ks)                                                            \
    do {                                                                       \
        _Pragma("unroll") for (int n = 0; n < 4; ++n)                          \
            bfr[n] = *(const bf16x8*)&Bs[b][ks][bBase + n * 512];              \
    } while (0)
#define MFMA16(mh)                                                             \
    do {                                                                       \
        __builtin_amdgcn_s_setprio(1);                                         \
        _Pragma("unroll") for (int m = 0; m < 4; ++m)                          \
            _Pragma("unroll") for (int n = 0; n < 4; ++n)                      \
                acc[(mh) * 4 + m][n] = __builtin_amdgcn_mfma_f32_16x16x32_bf16(\
                    af[m], bfr[n], acc[(mh) * 4 + m][n], 0, 0, 0);             \
        __builtin_amdgcn_s_setprio(0);                                         \
    } while (0)
#define VMCNT(n) asm volatile("s_waitcnt vmcnt(" #n ")" ::: "memory")
#define BAR() __builtin_amdgcn_s_barrier()

    // prologue: stage all of tile 0 into buf 0 (issue order A0,B0,A1,B1)
    STAGE_A(0, 0, 0);
    STAGE_B(0, 0, 0);
    STAGE_A(0, 1, 0);
    STAGE_B(0, 1, 0);
    VMCNT(4);  // kh0 pair landed
    BAR();

    for (int t = 0; t < NT; ++t) {
        const int b = t & 1;
        const int koff = (t + 1) * BK;
        const bool st = (t + 1 < NT);
        // P0: ks=0, m-half 0 — prefetch t+1's kh0
        DS_A(b, 0, 0);
        DS_B(b, 0);
        if (st) { STAGE_A(b ^ 1, 0, koff); STAGE_B(b ^ 1, 0, koff); }
        BAR();
        MFMA16(0);
        BAR();
        // P1: ks=0, m-half 1 — prefetch t+1's kh1 (4 phases before its use)
        DS_A(b, 0, 1);
        if (st) { STAGE_A(b ^ 1, 1, koff); STAGE_B(b ^ 1, 1, koff); }
        BAR();
        MFMA16(1);
        if (st) VMCNT(8);   // retire this tile's kh1 pair (issued last tile P1)
        else    VMCNT(0);   // tail: only this tile's kh1 outstanding
        BAR();
        // P2: ks=1, m-half 0
        DS_A(b, 1, 0);
        DS_B(b, 1);
        BAR();
        MFMA16(0);
        BAR();
        // P3: ks=1, m-half 1
        DS_A(b, 1, 1);
        BAR();
        MFMA16(1);
        if (st) VMCNT(4);   // retire t+1's kh0 pair before next P0 reads it
        BAR();
    }

    // ---- fused epilogue ----
    // C/D layout: col = lane&15 (r16), row = g*4 + reg  [m89 verified]
    float* ssum = (float*)&As[0][0][0];   // 256*4 floats
    float* smx = ssum + 1024;             // 256*4 floats
    const int baseRowW = rowBase + wr * 128 + g * 4;
    const int baseColW = colBase + wc * 64 + r16;
    #pragma unroll
    for (int m = 0; m < 8; ++m) {
        #pragma unroll
        for (int reg = 0; reg < 4; ++reg) {
            const int i = baseRowW + m * 16 + reg;
            const int partner = i ^ BATCHD;
            float sum = 0.f, mx = -1e30f;
            #pragma unroll
            for (int n = 0; n < 4; ++n) {
                const int j = baseColW + n * 16;
                const float s = acc[m][n][reg];
                const bool isDiag = (j == i);
                const bool isPos = (j == partner);
                float e = __expf(s - SHIFT);
                if (isDiag) e = 0.f;
                sum += e;
                if (!isDiag && !isPos) mx = fmaxf(mx, s);
                if (isPos) rowpos[i] = s;  // exactly one writer grid-wide
            }
            #pragma unroll
            for (int off = 1; off < 16; off <<= 1) {
                sum += __shfl_xor(sum, off);
                mx = fmaxf(mx, __shfl_xor(mx, off));
            }
            if (r16 == 0) {
                const int rloc = wr * 128 + m * 16 + g * 4 + reg;
                ssum[rloc * 4 + wc] = sum;
                smx[rloc * 4 + wc] = mx;
            }
        }
    }
    __syncthreads();
    // combine the 4 column-waves' partials: one atomic pair per row per block
    if (tid < 256) {
        const float s = ssum[tid * 4 + 0] + ssum[tid * 4 + 1] +
                        ssum[tid * 4 + 2] + ssum[tid * 4 + 3];
        const float mx = fmaxf(fmaxf(smx[tid * 4 + 0], smx[tid * 4 + 1]),
                               fmaxf(smx[tid * 4 + 2], smx[tid * 4 + 3]));
        const int i = rowBase + tid;
        atomicAdd(&rowsum[i], s);
        atomicMax(&rowmax[i], f2u_ord(mx));
    }
#undef STAGE_A
#undef STAGE_B
#undef DS_A
#undef DS_B
#undef MFMA16
#undef VMCNT
#undef BAR
}

// 32 blocks x 256 threads: one row per thread, block-reduce, atomic combine.
__global__ __launch_bounds__(256) void finalize_partial(const float* __restrict__ rowsum,
                                                        const unsigned* __restrict__ rowmax,
                                                        const float* __restrict__ rowpos,
                                                        float* __restrict__ accum) {
    const int tid = threadIdx.x;
    const int i = blockIdx.x * 256 + tid;
    const float lse = SHIFT + logf(rowsum[i]);
    const float pos = rowpos[i];
    float lossAcc = lse - pos;
    float hitAcc = (pos >= u2f_ord(rowmax[i])) ? 1.f : 0.f;
    __shared__ float sl[256], sa[256];
    sl[tid] = lossAcc; sa[tid] = hitAcc;
    __syncthreads();
    for (int s = 128; s > 0; s >>= 1) {
        if (tid < s) { sl[tid] += sl[tid + s]; sa[tid] += sa[tid + s]; }
        __syncthreads();
    }
    if (tid == 0) {
        atomicAdd(&accum[0], sl[0]);
        atomicAdd(&accum[1], sa[0]);
    }
}

__global__ void finalize_write(const float* __restrict__ accum, float* __restrict__ out) {
    if (threadIdx.x == 0) {
        out[0] = accum[0] / (float)NROWS;
        out[1] = accum[1] / (float)NROWS;
    }
}

extern "C" void kernel_launch(void* const* d_in, const int* in_sizes, int n_in,
                              void* d_out, int out_size, void* d_ws, size_t ws_size,
                              hipStream_t stream) {
    const float* msg = (const float*)d_in[0];
    const float* img = (const float*)d_in[1];
    float* out = (float*)d_out;

    char* ws = (char*)d_ws;
    const size_t matBytes = (size_t)NROWS * DIM * sizeof(short);  // 8 MB
    short* mnb = (short*)ws;
    short* imb = (short*)(ws + matBytes);
    float* rowsum = (float*)(ws + 2 * matBytes);
    unsigned* rowmax = (unsigned*)(ws + 2 * matBytes + NROWS * sizeof(float));
    float* rowpos = (float*)(ws + 2 * matBytes + 2 * NROWS * sizeof(float));
    float* accum = (float*)(ws + 2 * matBytes + 3 * NROWS * sizeof(float));

    normalize_bf16_both<<<2 * NROWS, 64, 0, stream>>>(msg, img, mnb, imb,
                                                      rowsum, rowmax, accum);

    simloss_mfma<<<(NROWS / BM) * (NROWS / BN), 512, 0, stream>>>(mnb, imb, rowsum,
                                                                  rowmax, rowpos);

    finalize_partial<<<NROWS / 256, 256, 0, stream>>>(rowsum, rowmax, rowpos, accum);
    finalize_write<<<1, 64, 0, stream>>>(accum, out);
}

// Round 6
// 110.882 us; speedup vs baseline: 7.1045x; 1.0587x over previous
//
#include <hip/hip_runtime.h>
#include <hip/hip_bf16.h>

// NT-Xent, BATCH=4096, N=8192, D=512, TEMP=0.1 — bf16 MFMA, 256^2 tile,
// fully-unrolled 4-phase/K-tile schedule with one-phase ds_read read-ahead
// (double fragment registers), counted vmcnt, 1 barrier/phase, setprio.
// loss = mean_i [ logsumexp_{j!=i} sim[i,j] - sim[i,partner(i)] ]
// acc  = mean_i [ sim[i,partner(i)] >= max_{j!=i,partner} sim[i,j] ]
// sim = (msg_n . img_n^T)/TEMP, 10x folded into msg side before bf16 cast.

#define NROWS 8192
#define BATCHD 4096
#define DIM 512
#define BM 256
#define BN 256
#define BK 64
#define NT (DIM / BK)   // 8 K-tiles
#define SHIFT 10.0f

typedef short bf16x8 __attribute__((ext_vector_type(8)));
typedef float f32x4 __attribute__((ext_vector_type(4)));

#define GLDS(g, l)                                                             \
    __builtin_amdgcn_global_load_lds(                                          \
        (const __attribute__((address_space(1))) void*)(g),                    \
        (__attribute__((address_space(3))) void*)(l), 16, 0, 0)

__device__ __forceinline__ unsigned f2u_ord(float f) {
    unsigned u = __float_as_uint(f);
    return (u & 0x80000000u) ? ~u : (u | 0x80000000u);
}
__device__ __forceinline__ float u2f_ord(unsigned e) {
    return (e & 0x80000000u) ? __uint_as_float(e & 0x7fffffffu) : __uint_as_float(~e);
}
__device__ __forceinline__ short f2bf(float f) {  // RNE f32 -> bf16 bits
    unsigned u = __float_as_uint(f);
    return (short)((u + 0x7fffu + ((u >> 16) & 1u)) >> 16);
}

// blocks 0..NROWS-1: msg (x10); NROWS..2*NROWS-1: img (x1).
// First 128 blocks also zero rowsum/rowmax/accum.
__global__ __launch_bounds__(64) void normalize_bf16_both(const float* __restrict__ msg,
                                                          const float* __restrict__ img,
                                                          short* __restrict__ mnb,
                                                          short* __restrict__ imb,
                                                          float* __restrict__ rowsum,
                                                          unsigned* __restrict__ rowmax,
                                                          float* __restrict__ accum) {
    if (blockIdx.x < 128) {
        const int i = blockIdx.x * 64 + threadIdx.x;
        rowsum[i] = 0.f;
        rowmax[i] = 0u;  // encodes "most negative"
        if (i < 2) accum[i] = 0.f;
    }
    int row = blockIdx.x;
    const float* in;
    short* out;
    float scale;
    if (row < NROWS) { in = msg; out = mnb; scale = 10.0f; }
    else { row -= NROWS; in = img; out = imb; scale = 1.0f; }
    const int lane = threadIdx.x;
    const float* src = in + (size_t)row * DIM + lane * 8;
    float4 v0 = *(const float4*)(src);
    float4 v1 = *(const float4*)(src + 4);
    float ss = v0.x*v0.x + v0.y*v0.y + v0.z*v0.z + v0.w*v0.w
             + v1.x*v1.x + v1.y*v1.y + v1.z*v1.z + v1.w*v1.w;
    #pragma unroll
    for (int off = 1; off < 64; off <<= 1) ss += __shfl_xor(ss, off);
    const float inv = scale / fmaxf(sqrtf(ss), 1e-8f);
    float vv[8] = {v0.x, v0.y, v0.z, v0.w, v1.x, v1.y, v1.z, v1.w};
    bf16x8 o;
    #pragma unroll
    for (int j = 0; j < 8; ++j) o[j] = f2bf(vv[j] * inv);
    *(bf16x8*)(out + (size_t)row * DIM + lane * 8) = o;
}

// A = msg_n*10 (bf16), B = img_n (bf16); row-major [8192][512].
// 256x256 tile, 8 waves (2M x 4N), BK=64 as 2 K-halves of 32.
// Per K-half LDS layout: [256 rows][4 chunks of 16B], chunk ^= (row>>1)&3
// (verified 0-conflict); linear GLDS dest, pre-swizzled global source.
__global__ __launch_bounds__(512, 2) void simloss_mfma(const short* __restrict__ A,
                                                       const short* __restrict__ B,
                                                       float* __restrict__ rowsum,
                                                       unsigned* __restrict__ rowmax,
                                                       float* __restrict__ rowpos) {
    __shared__ short As[2][2][BM * 32];  // [buf][khalf] = 64 KB
    __shared__ short Bs[2][2][BN * 32];  // 64 KB

    const int tid = threadIdx.x;
    const int lane = tid & 63;
    const int g = lane >> 4;     // k-chunk 0..3 within a K-half
    const int r16 = lane & 15;
    const int wid = tid >> 6;
    const int wr = wid >> 2;     // 0..1  (M waves)
    const int wc = wid & 3;      // 0..3  (N waves)

    // XCD stripes, bx-major traversal (by fastest) -> small L2 working set.
    const int bid = blockIdx.x;
    const int k = bid & 7;           // XCD (round-robin dispatch)
    const int l = bid >> 3;          // 0..127 within stripe
    const int by = k * 4 + (l & 3);
    const int bx = l >> 2;
    const int rowBase = by * BM;
    const int colBase = bx * BN;

    // staging: slot s = q*512+tid; row=s>>2; stored chunk=s&3;
    // logical chunk fetched = stored ^ ((row>>1)&3)  [inverse of read swizzle]
    const int s0 = tid, s1 = 512 + tid;
    const int row0 = s0 >> 2, row1 = s1 >> 2;
    const int c0 = (s0 & 3) ^ ((row0 >> 1) & 3);
    const int c1 = (s1 & 3) ^ ((row1 >> 1) & 3);
    const short* gA0 = A + (size_t)(rowBase + row0) * DIM + c0 * 8;
    const short* gA1 = A + (size_t)(rowBase + row1) * DIM + c1 * 8;
    const short* gB0 = B + (size_t)(colBase + row0) * DIM + c0 * 8;
    const short* gB1 = B + (size_t)(colBase + row1) * DIM + c1 * 8;

#define STAGE_A(b, kh, koff)                                        \
    do {                                                            \
        GLDS(gA0 + (koff) + (kh) * 32, &As[b][kh][tid * 8]);        \
        GLDS(gA1 + (koff) + (kh) * 32, &As[b][kh][4096 + tid * 8]); \
    } while (0)
#define STAGE_B(b, kh, koff)                                        \
    do {                                                            \
        GLDS(gB0 + (koff) + (kh) * 32, &Bs[b][kh][tid * 8]);        \
        GLDS(gB1 + (koff) + (kh) * 32, &Bs[b][kh][4096 + tid * 8]); \
    } while (0)

    // fragment read bases (elements); same XOR on read side
    const int swz = (r16 >> 1) & 3;
    const int aBase = (wr * 128 + r16) * 32 + ((g ^ swz) * 8);
    const int bBase = (wc * 64 + r16) * 32 + ((g ^ swz) * 8);

    f32x4 acc[8][4] = {};
    bf16x8 aR0[4], aR1[4], bR0[4], bR1[4];  // double fragment buffers

#define READ_A(b, ks, mh, dst)                                                  \
    do {                                                                        \
        _Pragma("unroll") for (int m = 0; m < 4; ++m)                           \
            dst[m] = *(const bf16x8*)&As[b][ks][aBase + (mh) * 2048 + m * 512]; \
    } while (0)
#define READ_B(b, ks, dst)                                                      \
    do {                                                                        \
        _Pragma("unroll") for (int n = 0; n < 4; ++n)                           \
            dst[n] = *(const bf16x8*)&Bs[b][ks][bBase + n * 512];               \
    } while (0)
#define MFMA16(mh, Af, Bf)                                                     \
    do {                                                                       \
        __builtin_amdgcn_s_setprio(1);                                         \
        _Pragma("unroll") for (int m = 0; m < 4; ++m)                          \
            _Pragma("unroll") for (int n = 0; n < 4; ++n)                      \
                acc[(mh) * 4 + m][n] = __builtin_amdgcn_mfma_f32_16x16x32_bf16(\
                    Af[m], Bf[n], acc[(mh) * 4 + m][n], 0, 0, 0);              \
        __builtin_amdgcn_s_setprio(0);                                         \
    } while (0)
#define VMCNT(n) asm volatile("s_waitcnt vmcnt(" #n ")" ::: "memory")
#define BAR() __builtin_amdgcn_s_barrier()

    // prologue: stage all of tile 0 into buf 0 (order: Akh0,Bkh0,Akh1,Bkh1)
    STAGE_A(0, 0, 0);
    STAGE_B(0, 0, 0);
    STAGE_A(0, 1, 0);
    STAGE_B(0, 1, 0);
    VMCNT(4);  // kh0 pair landed (4 newest = kh1 still in flight)
    BAR();
    READ_A(0, 0, 0, aR0);  // frags for (0,p0)
    READ_B(0, 0, bR0);

    #pragma unroll
    for (int t = 0; t < NT; ++t) {
        const int b = t & 1;
        const int koff = (t + 1) * BK;
        // ---- p0: MFMA(mh0,ks0); read p1 frags; stage t+1 kh0 ----
        BAR();
        if (t < NT - 1) { STAGE_A(b ^ 1, 0, koff); STAGE_B(b ^ 1, 0, koff); }
        READ_A(b, 0, 1, aR1);
        MFMA16(0, aR0, bR0);
        // ---- p1: MFMA(mh1,ks0); read p2 frags; stage t+1 kh1 ----
        if (t < NT - 1) VMCNT(4);  // this tile's kh1 landed (t+1 kh0 in flight)
        else            VMCNT(0);  // tail: only kh1 outstanding
        BAR();
        if (t < NT - 1) { STAGE_A(b ^ 1, 1, koff); STAGE_B(b ^ 1, 1, koff); }
        READ_A(b, 1, 0, aR0);
        READ_B(b, 1, bR1);
        MFMA16(1, aR1, bR0);
        // ---- p2: MFMA(mh0,ks1); read p3 frags ----
        BAR();
        READ_A(b, 1, 1, aR1);
        MFMA16(0, aR0, bR1);
        // ---- p3: MFMA(mh1,ks1); read next tile's p0 frags ----
        if (t < NT - 1) VMCNT(4);  // t+1 kh0 landed (t+1 kh1 in flight)
        BAR();
        if (t < NT - 1) {
            READ_A(b ^ 1, 0, 0, aR0);
            READ_B(b ^ 1, 0, bR0);
        }
        MFMA16(1, aR1, bR1);
    }

    // ---- fused epilogue ----
    // C/D layout: col = lane&15 (r16), row = g*4 + reg  [m89 verified]
    __syncthreads();                      // drain everything; reuse LDS
    float* ssum = (float*)&As[0][0][0];   // 256*4 floats
    float* smx = ssum + 1024;             // 256*4 floats
    const int baseRowW = rowBase + wr * 128 + g * 4;
    const int baseColW = colBase + wc * 64 + r16;
    #pragma unroll
    for (int m = 0; m < 8; ++m) {
        #pragma unroll
        for (int reg = 0; reg < 4; ++reg) {
            const int i = baseRowW + m * 16 + reg;
            const int partner = i ^ BATCHD;
            float sum = 0.f, mx = -1e30f;
            #pragma unroll
            for (int n = 0; n < 4; ++n) {
                const int j = baseColW + n * 16;
                const float s = acc[m][n][reg];
                const bool isDiag = (j == i);
                const bool isPos = (j == partner);
                float e = __expf(s - SHIFT);
                if (isDiag) e = 0.f;
                sum += e;
                if (!isDiag && !isPos) mx = fmaxf(mx, s);
                if (isPos) rowpos[i] = s;  // exactly one writer grid-wide
            }
            #pragma unroll
            for (int off = 1; off < 16; off <<= 1) {
                sum += __shfl_xor(sum, off);
                mx = fmaxf(mx, __shfl_xor(mx, off));
            }
            if (r16 == 0) {
                const int rloc = wr * 128 + m * 16 + g * 4 + reg;
                ssum[rloc * 4 + wc] = sum;
                smx[rloc * 4 + wc] = mx;
            }
        }
    }
    __syncthreads();
    // combine the 4 column-waves' partials: one atomic pair per row per block
    if (tid < 256) {
        const float s = ssum[tid * 4 + 0] + ssum[tid * 4 + 1] +
                        ssum[tid * 4 + 2] + ssum[tid * 4 + 3];
        const float mx = fmaxf(fmaxf(smx[tid * 4 + 0], smx[tid * 4 + 1]),
                               fmaxf(smx[tid * 4 + 2], smx[tid * 4 + 3]));
        const int i = rowBase + tid;
        atomicAdd(&rowsum[i], s);
        atomicMax(&rowmax[i], f2u_ord(mx));
    }
#undef STAGE_A
#undef STAGE_B
#undef READ_A
#undef READ_B
#undef MFMA16
#undef VMCNT
#undef BAR
}

// 32 blocks x 256 threads: one row per thread, block-reduce, atomic combine.
__global__ __launch_bounds__(256) void finalize_partial(const float* __restrict__ rowsum,
                                                        const unsigned* __restrict__ rowmax,
                                                        const float* __restrict__ rowpos,
                                                        float* __restrict__ accum) {
    const int tid = threadIdx.x;
    const int i = blockIdx.x * 256 + tid;
    const float lse = SHIFT + logf(rowsum[i]);
    const float pos = rowpos[i];
    float lossAcc = lse - pos;
    float hitAcc = (pos >= u2f_ord(rowmax[i])) ? 1.f : 0.f;
    __shared__ float sl[256], sa[256];
    sl[tid] = lossAcc; sa[tid] = hitAcc;
    __syncthreads();
    for (int s = 128; s > 0; s >>= 1) {
        if (tid < s) { sl[tid] += sl[tid + s]; sa[tid] += sa[tid + s]; }
        __syncthreads();
    }
    if (tid == 0) {
        atomicAdd(&accum[0], sl[0]);
        atomicAdd(&accum[1], sa[0]);
    }
}

__global__ void finalize_write(const float* __restrict__ accum, float* __restrict__ out) {
    if (threadIdx.x == 0) {
        out[0] = accum[0] / (float)NROWS;
        out[1] = accum[1] / (float)NROWS;
    }
}

extern "C" void kernel_launch(void* const* d_in, const int* in_sizes, int n_in,
                              void* d_out, int out_size, void* d_ws, size_t ws_size,
                              hipStream_t stream) {
    const float* msg = (const float*)d_in[0];
    const float* img = (const float*)d_in[1];
    float* out = (float*)d_out;

    char* ws = (char*)d_ws;
    const size_t matBytes = (size_t)NROWS * DIM * sizeof(short);  // 8 MB
    short* mnb = (short*)ws;
    short* imb = (short*)(ws + matBytes);
    float* rowsum = (float*)(ws + 2 * matBytes);
    unsigned* rowmax = (unsigned*)(ws + 2 * matBytes + NROWS * sizeof(float));
    float* rowpos = (float*)(ws + 2 * matBytes + 2 * NROWS * sizeof(float));
    float* accum = (float*)(ws + 2 * matBytes + 3 * NROWS * sizeof(float));

    normalize_bf16_both<<<2 * NROWS, 64, 0, stream>>>(msg, img, mnb, imb,
                                                      rowsum, rowmax, accum);

    simloss_mfma<<<(NROWS / BM) * (NROWS / BN), 512, 0, stream>>>(mnb, imb, rowsum,
                                                                  rowmax, rowpos);

    finalize_partial<<<NROWS / 256, 256, 0, stream>>>(rowsum, rowmax, rowpos, accum);
    finalize_write<<<1, 64, 0, stream>>>(accum, out);
}

// Round 7
// 100.309 us; speedup vs baseline: 7.8534x; 1.1054x over previous
//
#include <hip/hip_runtime.h>
#include <hip/hip_bf16.h>

// NT-Xent, BATCH=4096, N=8192, D=512, TEMP=0.1 — bf16 MFMA.
// Round 7: 128x256 tile, BK=32, 512 thr, 48 KB LDS, <=128 VGPR target
// -> 2 independent blocks/CU for cross-block latency hiding (m97 mechanism).
// loss = mean_i [ logsumexp_{j!=i} sim[i,j] - sim[i,partner(i)] ]
// acc  = mean_i [ sim[i,partner(i)] >= max_{j!=i,partner} sim[i,j] ]
// sim = (msg_n . img_n^T)/TEMP, 10x folded into msg side before bf16 cast.

#define NROWS 8192
#define BATCHD 4096
#define DIM 512
#define BM 128
#define BN 256
#define BK 32
#define NT2 (DIM / BK)   // 16 K-tiles
#define SHIFT 10.0f

typedef short bf16x8 __attribute__((ext_vector_type(8)));
typedef float f32x4 __attribute__((ext_vector_type(4)));

#define GLDS(g, l)                                                             \
    __builtin_amdgcn_global_load_lds(                                          \
        (const __attribute__((address_space(1))) void*)(g),                    \
        (__attribute__((address_space(3))) void*)(l), 16, 0, 0)

__device__ __forceinline__ unsigned f2u_ord(float f) {
    unsigned u = __float_as_uint(f);
    return (u & 0x80000000u) ? ~u : (u | 0x80000000u);
}
__device__ __forceinline__ float u2f_ord(unsigned e) {
    return (e & 0x80000000u) ? __uint_as_float(e & 0x7fffffffu) : __uint_as_float(~e);
}
__device__ __forceinline__ short f2bf(float f) {  // RNE f32 -> bf16 bits
    unsigned u = __float_as_uint(f);
    return (short)((u + 0x7fffu + ((u >> 16) & 1u)) >> 16);
}

// blocks 0..NROWS-1: msg (x10); NROWS..2*NROWS-1: img (x1).
// First 128 blocks also zero rowsum/rowmax/accum.
__global__ __launch_bounds__(64) void normalize_bf16_both(const float* __restrict__ msg,
                                                          const float* __restrict__ img,
                                                          short* __restrict__ mnb,
                                                          short* __restrict__ imb,
                                                          float* __restrict__ rowsum,
                                                          unsigned* __restrict__ rowmax,
                                                          float* __restrict__ accum) {
    if (blockIdx.x < 128) {
        const int i = blockIdx.x * 64 + threadIdx.x;
        rowsum[i] = 0.f;
        rowmax[i] = 0u;  // encodes "most negative"
        if (i < 2) accum[i] = 0.f;
    }
    int row = blockIdx.x;
    const float* in;
    short* out;
    float scale;
    if (row < NROWS) { in = msg; out = mnb; scale = 10.0f; }
    else { row -= NROWS; in = img; out = imb; scale = 1.0f; }
    const int lane = threadIdx.x;
    const float* src = in + (size_t)row * DIM + lane * 8;
    float4 v0 = *(const float4*)(src);
    float4 v1 = *(const float4*)(src + 4);
    float ss = v0.x*v0.x + v0.y*v0.y + v0.z*v0.z + v0.w*v0.w
             + v1.x*v1.x + v1.y*v1.y + v1.z*v1.z + v1.w*v1.w;
    #pragma unroll
    for (int off = 1; off < 64; off <<= 1) ss += __shfl_xor(ss, off);
    const float inv = scale / fmaxf(sqrtf(ss), 1e-8f);
    float vv[8] = {v0.x, v0.y, v0.z, v0.w, v1.x, v1.y, v1.z, v1.w};
    bf16x8 o;
    #pragma unroll
    for (int j = 0; j < 8; ++j) o[j] = f2bf(vv[j] * inv);
    *(bf16x8*)(out + (size_t)row * DIM + lane * 8) = o;
}

// A = msg_n*10 (bf16), B = img_n (bf16); row-major [8192][512].
// 128x256 tile, 8 waves (2M x 4N, per-wave 64x64), BK=32.
// LDS layout per buffer: [rows][4 chunks of 16B], chunk ^= (row>>1)&3
// (verified 0-conflict); linear GLDS dest, pre-swizzled global source.
__global__ __launch_bounds__(512, 4) void simloss_mfma(const short* __restrict__ A,
                                                       const short* __restrict__ B,
                                                       float* __restrict__ rowsum,
                                                       unsigned* __restrict__ rowmax,
                                                       float* __restrict__ rowpos) {
    __shared__ short As[2][BM * BK];  // 2 x 8 KB
    __shared__ short Bs[2][BN * BK];  // 2 x 16 KB   -> 48 KB total

    const int tid = threadIdx.x;
    const int lane = tid & 63;
    const int g = lane >> 4;     // k-chunk 0..3
    const int r16 = lane & 15;
    const int wid = tid >> 6;
    const int wr = wid >> 2;     // 0..1  (M waves)
    const int wc = wid & 3;      // 0..3  (N waves)

    // XCD stripes, bx-major traversal (by fastest): 2048 blocks = 64 by x 32 bx.
    // XCD k owns by in [k*8, k*8+8); L2 WS ~ A-stripe 1MB + ~8 B panels 2MB.
    const int bid = blockIdx.x;
    const int xcd = bid & 7;
    const int l = bid >> 3;          // 0..255
    const int by = xcd * 8 + (l & 7);
    const int bx = l >> 3;           // 0..31
    const int rowBase = by * BM;
    const int colBase = bx * BN;

    // staging: thread -> (row = tid>>2, chunk-slot = tid&3); fetch logical
    // chunk = slot ^ ((row>>1)&3) (inverse of read swizzle). B has 256 rows:
    // second half at +128 rows; swz((r+128)) == swz(r), so same chunk offset.
    const int srow = tid >> 2;
    const int sc = (tid & 3) ^ ((srow >> 1) & 3);
    const short* gA = A + (size_t)(rowBase + srow) * DIM + sc * 8;
    const short* gB = B + (size_t)(colBase + srow) * DIM + sc * 8;

#define STAGE(b, koff)                                      \
    do {                                                    \
        GLDS(gA + (koff), &As[b][tid * 8]);                 \
        GLDS(gB + (koff), &Bs[b][tid * 8]);                 \
        GLDS(gB + 128 * DIM + (koff), &Bs[b][4096 + tid * 8]); \
    } while (0)

    // fragment read bases (elements); same XOR on read side
    const int swz = (r16 >> 1) & 3;
    const int aBase = (wr * 64 + r16) * BK + ((g ^ swz) * 8);
    const int bBase = (wc * 64 + r16) * BK + ((g ^ swz) * 8);

    f32x4 acc[4][4] = {};

#define VMCNT(n) asm volatile("s_waitcnt vmcnt(" #n ")" ::: "memory")
#define BAR() __builtin_amdgcn_s_barrier()

    // prologue: stage tile 0
    STAGE(0, 0);

    for (int t = 0; t < NT2; ++t) {
        const int b = t & 1;
        if (t < NT2 - 1) {
            STAGE(b ^ 1, (t + 1) * BK);  // 3 GLDS for t+1 in flight over compute
            VMCNT(3);                    // tile t's 3 GLDS landed
        } else {
            VMCNT(0);                    // tail: only t's 3 outstanding
        }
        BAR();                           // all waves see buf b staged
        bf16x8 af[4], bfr[4];
        #pragma unroll
        for (int m = 0; m < 4; ++m)
            af[m] = *(const bf16x8*)&As[b][aBase + m * 16 * BK];
        #pragma unroll
        for (int n = 0; n < 4; ++n)
            bfr[n] = *(const bf16x8*)&Bs[b][bBase + n * 16 * BK];
        __builtin_amdgcn_s_setprio(1);
        #pragma unroll
        for (int m = 0; m < 4; ++m)
            #pragma unroll
            for (int n = 0; n < 4; ++n)
                acc[m][n] = __builtin_amdgcn_mfma_f32_16x16x32_bf16(
                    af[m], bfr[n], acc[m][n], 0, 0, 0);
        __builtin_amdgcn_s_setprio(0);
        BAR();  // all waves done reading buf b (ds_reads consumed by MFMA)
    }

    // ---- fused epilogue ----
    // C/D layout: col = lane&15 (r16), row = g*4 + reg  [m89 verified]
    __syncthreads();                      // full drain; reuse LDS
    float* ssum = (float*)&As[0][0];      // 128*4 floats
    float* smx = ssum + 512;              // 128*4 floats
    const int baseRowW = rowBase + wr * 64 + g * 4;
    const int baseColW = colBase + wc * 64 + r16;
    #pragma unroll
    for (int m = 0; m < 4; ++m) {
        #pragma unroll
        for (int reg = 0; reg < 4; ++reg) {
            const int i = baseRowW + m * 16 + reg;
            const int partner = i ^ BATCHD;
            float sum = 0.f, mx = -1e30f;
            #pragma unroll
            for (int n = 0; n < 4; ++n) {
                const int j = baseColW + n * 16;
                const float s = acc[m][n][reg];
                const bool isDiag = (j == i);
                const bool isPos = (j == partner);
                float e = __expf(s - SHIFT);
                if (isDiag) e = 0.f;
                sum += e;
                if (!isDiag && !isPos) mx = fmaxf(mx, s);
                if (isPos) rowpos[i] = s;  // exactly one writer grid-wide
            }
            #pragma unroll
            for (int off = 1; off < 16; off <<= 1) {
                sum += __shfl_xor(sum, off);
                mx = fmaxf(mx, __shfl_xor(mx, off));
            }
            if (r16 == 0) {
                const int rloc = wr * 64 + m * 16 + g * 4 + reg;
                ssum[rloc * 4 + wc] = sum;
                smx[rloc * 4 + wc] = mx;
            }
        }
    }
    __syncthreads();
    // combine the 4 column-waves' partials: one atomic pair per row per block
    if (tid < BM) {
        const float s = ssum[tid * 4 + 0] + ssum[tid * 4 + 1] +
                        ssum[tid * 4 + 2] + ssum[tid * 4 + 3];
        const float mx = fmaxf(fmaxf(smx[tid * 4 + 0], smx[tid * 4 + 1]),
                               fmaxf(smx[tid * 4 + 2], smx[tid * 4 + 3]));
        const int i = rowBase + tid;
        atomicAdd(&rowsum[i], s);
        atomicMax(&rowmax[i], f2u_ord(mx));
    }
#undef STAGE
#undef VMCNT
#undef BAR
}

// 32 blocks x 256 threads: one row per thread, block-reduce, atomic combine.
__global__ __launch_bounds__(256) void finalize_partial(const float* __restrict__ rowsum,
                                                        const unsigned* __restrict__ rowmax,
                                                        const float* __restrict__ rowpos,
                                                        float* __restrict__ accum) {
    const int tid = threadIdx.x;
    const int i = blockIdx.x * 256 + tid;
    const float lse = SHIFT + logf(rowsum[i]);
    const float pos = rowpos[i];
    float lossAcc = lse - pos;
    float hitAcc = (pos >= u2f_ord(rowmax[i])) ? 1.f : 0.f;
    __shared__ float sl[256], sa[256];
    sl[tid] = lossAcc; sa[tid] = hitAcc;
    __syncthreads();
    for (int s = 128; s > 0; s >>= 1) {
        if (tid < s) { sl[tid] += sl[tid + s]; sa[tid] += sa[tid + s]; }
        __syncthreads();
    }
    if (tid == 0) {
        atomicAdd(&accum[0], sl[0]);
        atomicAdd(&accum[1], sa[0]);
    }
}

__global__ void finalize_write(const float* __restrict__ accum, float* __restrict__ out) {
    if (threadIdx.x == 0) {
        out[0] = accum[0] / (float)NROWS;
        out[1] = accum[1] / (float)NROWS;
    }
}

extern "C" void kernel_launch(void* const* d_in, const int* in_sizes, int n_in,
                              void* d_out, int out_size, void* d_ws, size_t ws_size,
                              hipStream_t stream) {
    const float* msg = (const float*)d_in[0];
    const float* img = (const float*)d_in[1];
    float* out = (float*)d_out;

    char* ws = (char*)d_ws;
    const size_t matBytes = (size_t)NROWS * DIM * sizeof(short);  // 8 MB
    short* mnb = (short*)ws;
    short* imb = (short*)(ws + matBytes);
    float* rowsum = (float*)(ws + 2 * matBytes);
    unsigned* rowmax = (unsigned*)(ws + 2 * matBytes + NROWS * sizeof(float));
    float* rowpos = (float*)(ws + 2 * matBytes + 2 * NROWS * sizeof(float));
    float* accum = (float*)(ws + 2 * matBytes + 3 * NROWS * sizeof(float));

    normalize_bf16_both<<<2 * NROWS, 64, 0, stream>>>(msg, img, mnb, imb,
                                                      rowsum, rowmax, accum);

    simloss_mfma<<<(NROWS / BM) * (NROWS / BN), 512, 0, stream>>>(mnb, imb, rowsum,
                                                                  rowmax, rowpos);

    finalize_partial<<<NROWS / 256, 256, 0, stream>>>(rowsum, rowmax, rowpos, accum);
    finalize_write<<<1, 64, 0, stream>>>(accum, out);
}